// Round 3
// baseline (2547.830 us; speedup 1.0000x reference)
//
#include <hip/hip_runtime.h>
#include <hip/hip_bf16.h>

// ---------------------------------------------------------------------------
// row_ptr build from sorted adj_row
// ---------------------------------------------------------------------------
__global__ void build_rowptr(const int* __restrict__ row, int* __restrict__ rp,
                             int E, int N) {
    int e = blockIdx.x * blockDim.x + threadIdx.x;
    if (e >= E) return;
    int r = row[e];
    int rprev = (e == 0) ? -1 : row[e - 1];
    for (int q = rprev + 1; q <= r; ++q) rp[q] = e;
    if (e == E - 1) {
        for (int q = r + 1; q <= N; ++q) rp[q] = E;
    }
}

// ---------------------------------------------------------------------------
// Simple fp32 GEMM: S = H[N,CIN] @ W[CIN,COUT]. One thread per output elem.
// W read from global (128KB max -> L1/L2 resident, coalesced across c).
// Diagnostic round: correctness over speed.
// ---------------------------------------------------------------------------
template <int CIN, int COUT>
__global__ __launch_bounds__(256) void gemm_simple(
    const float* __restrict__ H, const float* __restrict__ W,
    float* __restrict__ S, int Nrows) {
    constexpr int RPB = 256 / COUT;  // rows per block
    int c = threadIdx.x % COUT;
    int rsub = threadIdx.x / COUT;
    int row = blockIdx.x * RPB + rsub;
    if (row >= Nrows) return;

    const float* hrow = H + (size_t)row * CIN;
    float acc = 0.f;
#pragma unroll 8
    for (int k = 0; k < CIN; ++k) {
        acc += hrow[k] * W[k * COUT + c];
    }
    S[(size_t)row * COUT + c] = acc;
}

// ---------------------------------------------------------------------------
// SpMM + fused activation: Ag[n,c] = act( sum_e vals[e]*S[col[e],c] )
// act(x) = x>=0 ? x : expm1(0.2x)   (elu o leaky_relu)
// ---------------------------------------------------------------------------
template <int C>
__global__ __launch_bounds__(128) void spmm_act(
    const float* __restrict__ S, const int* __restrict__ colIdx,
    const float* __restrict__ vals, const int* __restrict__ rowPtr,
    float* __restrict__ Ag, int N) {
    constexpr int NPB = 128 / C;
    int sub = threadIdx.x / C;
    int c = threadIdx.x % C;
    int node = blockIdx.x * NPB + sub;
    if (node >= N) return;
    int e0 = rowPtr[node], e1 = rowPtr[node + 1];
    float acc = 0.f;
    for (int e = e0; e < e1; ++e) {
        int cc = colIdx[e];
        acc += vals[e] * S[(size_t)cc * C + c];
    }
    Ag[(size_t)node * C + c] = acc >= 0.f ? acc : expm1f(0.2f * acc);
}

// ---------------------------------------------------------------------------
// BN stats: per-column sum & sumsq (fp32), atomics into stats[0..C) / [C..2C)
// ---------------------------------------------------------------------------
template <int C>
__global__ __launch_bounds__(256) void bn_stats(
    const float* __restrict__ Ag, float* __restrict__ stats, int N) {
    constexpr int RPB = 256 / C;
    int c = threadIdx.x % C;
    int rg = threadIdx.x / C;
    float s = 0.f, s2 = 0.f;
    for (int r = blockIdx.x * RPB + rg; r < N; r += gridDim.x * RPB) {
        float x = Ag[(size_t)r * C + c];
        s += x;
        s2 += x * x;
    }
    __shared__ float ls[256], ls2[256];
    ls[threadIdx.x] = s;
    ls2[threadIdx.x] = s2;
    __syncthreads();
    if (rg == 0) {
#pragma unroll
        for (int g = 1; g < RPB; ++g) {
            s += ls[g * C + c];
            s2 += ls2[g * C + c];
        }
        atomicAdd(&stats[c], s);
        atomicAdd(&stats[C + c], s2);
    }
}

// ---------------------------------------------------------------------------
// BN normalize IN PLACE: x = (x - mean) * rsqrt(max(var,0) + eps)
// ---------------------------------------------------------------------------
template <int C>
__global__ __launch_bounds__(256) void bn_norm(
    float* __restrict__ Ag, const float* __restrict__ stats, int N) {
    constexpr int RPB = 256 / C;
    int c = threadIdx.x % C;
    int rg = threadIdx.x / C;
    float invN = 1.f / (float)N;
    float mean = stats[c] * invN;
    float var = stats[C + c] * invN - mean * mean;
    float inv = rsqrtf(fmaxf(var, 0.f) + 1e-5f);
    for (int r = blockIdx.x * RPB + rg; r < N; r += gridDim.x * RPB) {
        float x = Ag[(size_t)r * C + c];
        Ag[(size_t)r * C + c] = (x - mean) * inv;
    }
}

// ---------------------------------------------------------------------------
extern "C" void kernel_launch(void* const* d_in, const int* in_sizes, int n_in,
                              void* d_out, int out_size, void* d_ws,
                              size_t ws_size, hipStream_t stream) {
    const float* x = (const float*)d_in[0];
    const int* adj_row = (const int*)d_in[1];
    const int* adj_col = (const int*)d_in[2];
    const float* adj_vals = (const float*)d_in[3];
    const float* W1 = (const float*)d_in[4];
    const float* W2 = (const float*)d_in[5];
    const float* W3 = (const float*)d_in[6];
    const float* W4 = (const float*)d_in[7];

    int N = in_sizes[0] / 256;
    int E = in_sizes[1];

    // workspace carve: rp | stats | S   (~52 MB total)
    char* ws = (char*)d_ws;
    int* rp = (int*)ws;
    size_t off = (((size_t)(N + 1) * 4) + 255) & ~(size_t)255;
    float* stats = (float*)(ws + off);  // 4 layers x 256 floats
    off += 4 * 256 * sizeof(float);
    float* S = (float*)(ws + off);  // support, N*128 fp32

    hipMemsetAsync(stats, 0, 4 * 256 * sizeof(float), stream);
    build_rowptr<<<(E + 255) / 256, 256, 0, stream>>>(adj_row, rp, E, N);

    float* h1 = (float*)d_out;
    float* h2 = h1 + (size_t)N * 128;
    float* h3 = h2 + (size_t)N * 128;
    float* h4 = h3 + (size_t)N * 64;

    // layer 1: 256 -> 128
    gemm_simple<256, 128><<<(N + 1) / 2, 256, 0, stream>>>(x, W1, S, N);
    spmm_act<128><<<N, 128, 0, stream>>>(S, adj_col, adj_vals, rp, h1, N);
    bn_stats<128><<<256, 256, 0, stream>>>(h1, stats + 0, N);
    bn_norm<128><<<256, 256, 0, stream>>>(h1, stats + 0, N);

    // layer 2: 128 -> 128
    gemm_simple<128, 128><<<(N + 1) / 2, 256, 0, stream>>>(h1, W2, S, N);
    spmm_act<128><<<N, 128, 0, stream>>>(S, adj_col, adj_vals, rp, h2, N);
    bn_stats<128><<<256, 256, 0, stream>>>(h2, stats + 256, N);
    bn_norm<128><<<256, 256, 0, stream>>>(h2, stats + 256, N);

    // layer 3: 128 -> 64
    gemm_simple<128, 64><<<(N + 3) / 4, 256, 0, stream>>>(h2, W3, S, N);
    spmm_act<64><<<(N + 1) / 2, 128, 0, stream>>>(S, adj_col, adj_vals, rp, h3, N);
    bn_stats<64><<<256, 256, 0, stream>>>(h3, stats + 512, N);
    bn_norm<64><<<256, 256, 0, stream>>>(h3, stats + 512, N);

    // layer 4: 64 -> 32
    gemm_simple<64, 32><<<(N + 7) / 8, 256, 0, stream>>>(h3, W4, S, N);
    spmm_act<32><<<(N + 3) / 4, 128, 0, stream>>>(S, adj_col, adj_vals, rp, h4, N);
    bn_stats<32><<<256, 256, 0, stream>>>(h4, stats + 768, N);
    bn_norm<32><<<256, 256, 0, stream>>>(h4, stats + 768, N);
}

// Round 4
// 1338.837 us; speedup vs baseline: 1.9030x; 1.9030x over previous
//
#include <hip/hip_runtime.h>
#include <hip/hip_bf16.h>

typedef __attribute__((ext_vector_type(8))) short short8;
typedef __attribute__((ext_vector_type(4))) float floatx4;

// ---------------------------------------------------------------------------
// row_ptr build from sorted adj_row
// ---------------------------------------------------------------------------
__global__ void build_rowptr(const int* __restrict__ row, int* __restrict__ rp,
                             int E, int N) {
    int e = blockIdx.x * blockDim.x + threadIdx.x;
    if (e >= E) return;
    int r = row[e];
    int rprev = (e == 0) ? -1 : row[e - 1];
    for (int q = rprev + 1; q <= r; ++q) rp[q] = e;
    if (e == E - 1) {
        for (int q = r + 1; q <= N; ++q) rp[q] = E;
    }
}

// ---------------------------------------------------------------------------
// MFMA GEMM: S = H[N,CIN] @ W[CIN,COUT]; fp32 in/out, bf16 MFMA compute,
// fp32 accumulate. W transposed+XOR-swizzled into LDS as bf16 (2-way bank
// aliasing = free). Block = 4 waves x 16 rows = 64 rows/block.
// ---------------------------------------------------------------------------
template <int CIN, int COUT>
__global__ __launch_bounds__(256) void gemm_mfma(
    const float* __restrict__ H, const float* __restrict__ W,
    float* __restrict__ S, int Nrows) {
    // Wt: row n has CIN/8 chunks of 8 bf16; chunk kc stored at index kc^(n&7)
    __shared__ short Wt[CIN * COUT];
    constexpr int NCHUNK = CIN / 8;
    for (int i = threadIdx.x; i < CIN * COUT; i += 256) {
        int k = i / COUT, n = i % COUT;
        int kc = k >> 3, kr = k & 7;
        __hip_bfloat16 w = __float2bfloat16(W[i]);
        Wt[(n * NCHUNK + (kc ^ (n & 7))) * 8 + kr] = *(short*)&w;
    }
    __syncthreads();

    int wave = threadIdx.x >> 6, lane = threadIdx.x & 63;
    int m = lane & 15, quad = lane >> 4;
    int r0 = blockIdx.x * 64 + wave * 16;
    int rowi = r0 + m;
    int rowc = rowi < Nrows ? rowi : (Nrows - 1);

    // A fragments: A[m][k=quad*8+j], fp32 -> bf16, all k-steps in registers
    short8 a[CIN / 32];
    const float* hrow = H + (size_t)rowc * CIN;
#pragma unroll
    for (int ks = 0; ks < CIN / 32; ++ks) {
        const float* p = hrow + ks * 32 + quad * 8;
        short8 t;
#pragma unroll
        for (int j = 0; j < 8; ++j) {
            __hip_bfloat16 b = __float2bfloat16(p[j]);
            t[j] = *(short*)&b;
        }
        a[ks] = t;
    }

#pragma unroll
    for (int nt = 0; nt < COUT / 16; ++nt) {
        floatx4 acc = {0.f, 0.f, 0.f, 0.f};
        int n = nt * 16 + m;
#pragma unroll
        for (int ks = 0; ks < CIN / 32; ++ks) {
            int kc = ks * 4 + quad;
            short8 b = *(const short8*)(&Wt[(n * NCHUNK + (kc ^ (n & 7))) * 8]);
            acc = __builtin_amdgcn_mfma_f32_16x16x32_bf16(a[ks], b, acc, 0, 0, 0);
        }
        // C/D: col = lane&15, row = quad*4 + reg
#pragma unroll
        for (int reg = 0; reg < 4; ++reg) {
            int rr = r0 + quad * 4 + reg;
            if (rr < Nrows) S[(size_t)rr * COUT + n] = acc[reg];
        }
    }
}

// ---------------------------------------------------------------------------
// SpMM + fused activation: Ag[n,c] = act( sum_e vals[e]*S[col[e],c] )
// act(x) = x>=0 ? x : expm1(0.2x)   (elu o leaky_relu)
// ---------------------------------------------------------------------------
template <int C>
__global__ __launch_bounds__(128) void spmm_act(
    const float* __restrict__ S, const int* __restrict__ colIdx,
    const float* __restrict__ vals, const int* __restrict__ rowPtr,
    float* __restrict__ Ag, int N) {
    constexpr int NPB = 128 / C;
    int sub = threadIdx.x / C;
    int c = threadIdx.x % C;
    int node = blockIdx.x * NPB + sub;
    if (node >= N) return;
    int e0 = rowPtr[node], e1 = rowPtr[node + 1];
    float acc = 0.f;
    for (int e = e0; e < e1; ++e) {
        int cc = colIdx[e];
        acc += vals[e] * S[(size_t)cc * C + c];
    }
    Ag[(size_t)node * C + c] = acc >= 0.f ? acc : expm1f(0.2f * acc);
}

// ---------------------------------------------------------------------------
// BN stats: per-column sum & sumsq (fp32), atomics into stats[0..C) / [C..2C)
// ---------------------------------------------------------------------------
template <int C>
__global__ __launch_bounds__(256) void bn_stats(
    const float* __restrict__ Ag, float* __restrict__ stats, int N) {
    constexpr int RPB = 256 / C;
    int c = threadIdx.x % C;
    int rg = threadIdx.x / C;
    float s = 0.f, s2 = 0.f;
    for (int r = blockIdx.x * RPB + rg; r < N; r += gridDim.x * RPB) {
        float x = Ag[(size_t)r * C + c];
        s += x;
        s2 += x * x;
    }
    __shared__ float ls[256], ls2[256];
    ls[threadIdx.x] = s;
    ls2[threadIdx.x] = s2;
    __syncthreads();
    if (rg == 0) {
#pragma unroll
        for (int g = 1; g < RPB; ++g) {
            s += ls[g * C + c];
            s2 += ls2[g * C + c];
        }
        atomicAdd(&stats[c], s);
        atomicAdd(&stats[C + c], s2);
    }
}

// ---------------------------------------------------------------------------
// BN normalize IN PLACE: x = (x - mean) * rsqrt(max(var,0) + eps)
// ---------------------------------------------------------------------------
template <int C>
__global__ __launch_bounds__(256) void bn_norm(
    float* __restrict__ Ag, const float* __restrict__ stats, int N) {
    constexpr int RPB = 256 / C;
    int c = threadIdx.x % C;
    int rg = threadIdx.x / C;
    float invN = 1.f / (float)N;
    float mean = stats[c] * invN;
    float var = stats[C + c] * invN - mean * mean;
    float inv = rsqrtf(fmaxf(var, 0.f) + 1e-5f);
    for (int r = blockIdx.x * RPB + rg; r < N; r += gridDim.x * RPB) {
        float x = Ag[(size_t)r * C + c];
        Ag[(size_t)r * C + c] = (x - mean) * inv;
    }
}

// ---------------------------------------------------------------------------
extern "C" void kernel_launch(void* const* d_in, const int* in_sizes, int n_in,
                              void* d_out, int out_size, void* d_ws,
                              size_t ws_size, hipStream_t stream) {
    const float* x = (const float*)d_in[0];
    const int* adj_row = (const int*)d_in[1];
    const int* adj_col = (const int*)d_in[2];
    const float* adj_vals = (const float*)d_in[3];
    const float* W1 = (const float*)d_in[4];
    const float* W2 = (const float*)d_in[5];
    const float* W3 = (const float*)d_in[6];
    const float* W4 = (const float*)d_in[7];

    int N = in_sizes[0] / 256;
    int E = in_sizes[1];

    // workspace carve: rp | stats | S   (~52 MB total)
    char* ws = (char*)d_ws;
    int* rp = (int*)ws;
    size_t off = (((size_t)(N + 1) * 4) + 255) & ~(size_t)255;
    float* stats = (float*)(ws + off);  // 4 layers x 256 floats
    off += 4 * 256 * sizeof(float);
    float* S = (float*)(ws + off);  // support, N*128 fp32

    hipMemsetAsync(stats, 0, 4 * 256 * sizeof(float), stream);
    build_rowptr<<<(E + 255) / 256, 256, 0, stream>>>(adj_row, rp, E, N);

    float* h1 = (float*)d_out;
    float* h2 = h1 + (size_t)N * 128;
    float* h3 = h2 + (size_t)N * 128;
    float* h4 = h3 + (size_t)N * 64;

    int gblk = (N + 63) / 64;

    // layer 1: 256 -> 128
    gemm_mfma<256, 128><<<gblk, 256, 0, stream>>>(x, W1, S, N);
    spmm_act<128><<<N, 128, 0, stream>>>(S, adj_col, adj_vals, rp, h1, N);
    bn_stats<128><<<256, 256, 0, stream>>>(h1, stats + 0, N);
    bn_norm<128><<<256, 256, 0, stream>>>(h1, stats + 0, N);

    // layer 2: 128 -> 128
    gemm_mfma<128, 128><<<gblk, 256, 0, stream>>>(h1, W2, S, N);
    spmm_act<128><<<N, 128, 0, stream>>>(S, adj_col, adj_vals, rp, h2, N);
    bn_stats<128><<<256, 256, 0, stream>>>(h2, stats + 256, N);
    bn_norm<128><<<256, 256, 0, stream>>>(h2, stats + 256, N);

    // layer 3: 128 -> 64
    gemm_mfma<128, 64><<<gblk, 256, 0, stream>>>(h2, W3, S, N);
    spmm_act<64><<<(N + 1) / 2, 128, 0, stream>>>(S, adj_col, adj_vals, rp, h3, N);
    bn_stats<64><<<256, 256, 0, stream>>>(h3, stats + 512, N);
    bn_norm<64><<<256, 256, 0, stream>>>(h3, stats + 512, N);

    // layer 4: 64 -> 32
    gemm_mfma<64, 32><<<gblk, 256, 0, stream>>>(h3, W4, S, N);
    spmm_act<32><<<(N + 3) / 4, 128, 0, stream>>>(S, adj_col, adj_vals, rp, h4, N);
    bn_stats<32><<<256, 256, 0, stream>>>(h4, stats + 768, N);
    bn_norm<32><<<256, 256, 0, stream>>>(h4, stats + 768, N);
}

// Round 5
// 777.027 us; speedup vs baseline: 3.2789x; 1.7230x over previous
//
#include <hip/hip_runtime.h>
#include <hip/hip_bf16.h>

typedef __attribute__((ext_vector_type(8))) short short8;
typedef __attribute__((ext_vector_type(4))) float floatx4;
typedef __attribute__((ext_vector_type(4))) unsigned short ushortx4;

__device__ __forceinline__ float b2f(unsigned short u) {
    unsigned int t = ((unsigned int)u) << 16;
    return __uint_as_float(t);
}
__device__ __forceinline__ unsigned short f2b(float f) {
    __hip_bfloat16 b = __float2bfloat16(f);
    return *(unsigned short*)&b;
}
__device__ __forceinline__ float act_elu_lrelu(float x) {
    return x >= 0.f ? x : expm1f(0.2f * x);
}

// ---------------------------------------------------------------------------
// row_ptr build from sorted adj_row
// ---------------------------------------------------------------------------
__global__ void build_rowptr(const int* __restrict__ row, int* __restrict__ rp,
                             int E, int N) {
    int e = blockIdx.x * blockDim.x + threadIdx.x;
    if (e >= E) return;
    int r = row[e];
    int rprev = (e == 0) ? -1 : row[e - 1];
    for (int q = rprev + 1; q <= r; ++q) rp[q] = e;
    if (e == E - 1) {
        for (int q = r + 1; q <= N; ++q) rp[q] = E;
    }
}

// ---------------------------------------------------------------------------
// MFMA GEMM: S(bf16) = H[N,CIN](fp32) @ W[CIN,COUT](fp32->bf16); fp32 accum.
// W transposed+XOR-swizzled into LDS as bf16. 4 waves x 16 rows = 64/block.
// ---------------------------------------------------------------------------
template <int CIN, int COUT>
__global__ __launch_bounds__(256) void gemm_mfma(
    const float* __restrict__ H, const float* __restrict__ W,
    unsigned short* __restrict__ S, int Nrows) {
    __shared__ short Wt[CIN * COUT];
    constexpr int NCHUNK = CIN / 8;
    for (int i = threadIdx.x; i < CIN * COUT; i += 256) {
        int k = i / COUT, n = i % COUT;
        int kc = k >> 3, kr = k & 7;
        Wt[(n * NCHUNK + (kc ^ (n & 7))) * 8 + kr] = (short)f2b(W[i]);
    }
    __syncthreads();

    int wave = threadIdx.x >> 6, lane = threadIdx.x & 63;
    int m = lane & 15, quad = lane >> 4;
    int r0 = blockIdx.x * 64 + wave * 16;
    int rowi = r0 + m;
    int rowc = rowi < Nrows ? rowi : (Nrows - 1);

    // A fragments: A[m][k=quad*8+j], fp32 -> bf16, all k-steps in registers
    short8 a[CIN / 32];
    const float* hrow = H + (size_t)rowc * CIN;
#pragma unroll
    for (int ks = 0; ks < CIN / 32; ++ks) {
        const float* p = hrow + ks * 32 + quad * 8;
        short8 t;
#pragma unroll
        for (int j = 0; j < 8; ++j) t[j] = (short)f2b(p[j]);
        a[ks] = t;
    }

#pragma unroll
    for (int nt = 0; nt < COUT / 16; ++nt) {
        floatx4 acc = {0.f, 0.f, 0.f, 0.f};
        int n = nt * 16 + m;
#pragma unroll
        for (int ks = 0; ks < CIN / 32; ++ks) {
            int kc = ks * 4 + quad;
            short8 b = *(const short8*)(&Wt[(n * NCHUNK + (kc ^ (n & 7))) * 8]);
            acc = __builtin_amdgcn_mfma_f32_16x16x32_bf16(a[ks], b, acc, 0, 0, 0);
        }
        // C/D: col = lane&15, row = quad*4 + reg
#pragma unroll
        for (int reg = 0; reg < 4; ++reg) {
            int rr = r0 + quad * 4 + reg;
            if (rr < Nrows) S[(size_t)rr * COUT + n] = f2b(acc[reg]);
        }
    }
}

// ---------------------------------------------------------------------------
// SpMM + fused activation, bf16 gather source, fp32 accumulate/output.
// Each lane owns 4 consecutive cols (8B ushort4 gathers); edge loop x4
// unrolled with all gathers issued before the FMAs (latency hiding).
// ---------------------------------------------------------------------------
template <int C>
__global__ __launch_bounds__(256) void spmm_act_b(
    const ushortx4* __restrict__ S4, const int* __restrict__ colIdx,
    const float* __restrict__ vals, const int* __restrict__ rowPtr,
    float* __restrict__ Ag, int N) {
    constexpr int LPN = C / 4;      // lanes per node
    constexpr int NPB = 256 / LPN;  // nodes per block
    int sub = threadIdx.x / LPN;
    int lc = threadIdx.x % LPN;
    int node = blockIdx.x * NPB + sub;
    if (node >= N) return;
    int e0 = rowPtr[node], e1 = rowPtr[node + 1];

    float ax = 0.f, ay = 0.f, az = 0.f, aw = 0.f;
    int e = e0;
    for (; e + 4 <= e1; e += 4) {
        int i0 = colIdx[e], i1 = colIdx[e + 1];
        int i2 = colIdx[e + 2], i3 = colIdx[e + 3];
        float v0 = vals[e], v1 = vals[e + 1];
        float v2 = vals[e + 2], v3 = vals[e + 3];
        ushortx4 g0 = S4[(size_t)i0 * LPN + lc];
        ushortx4 g1 = S4[(size_t)i1 * LPN + lc];
        ushortx4 g2 = S4[(size_t)i2 * LPN + lc];
        ushortx4 g3 = S4[(size_t)i3 * LPN + lc];
        ax += v0 * b2f(g0.x) + v1 * b2f(g1.x) + v2 * b2f(g2.x) + v3 * b2f(g3.x);
        ay += v0 * b2f(g0.y) + v1 * b2f(g1.y) + v2 * b2f(g2.y) + v3 * b2f(g3.y);
        az += v0 * b2f(g0.z) + v1 * b2f(g1.z) + v2 * b2f(g2.z) + v3 * b2f(g3.z);
        aw += v0 * b2f(g0.w) + v1 * b2f(g1.w) + v2 * b2f(g2.w) + v3 * b2f(g3.w);
    }
    for (; e < e1; ++e) {
        int i0 = colIdx[e];
        float v0 = vals[e];
        ushortx4 g0 = S4[(size_t)i0 * LPN + lc];
        ax += v0 * b2f(g0.x);
        ay += v0 * b2f(g0.y);
        az += v0 * b2f(g0.z);
        aw += v0 * b2f(g0.w);
    }
    floatx4 r = {act_elu_lrelu(ax), act_elu_lrelu(ay), act_elu_lrelu(az),
                 act_elu_lrelu(aw)};
    *(floatx4*)&Ag[(size_t)node * C + lc * 4] = r;
}

// ---------------------------------------------------------------------------
// BN stats: per-column sum & sumsq (fp32), atomics into stats[0..C) / [C..2C)
// ---------------------------------------------------------------------------
template <int C>
__global__ __launch_bounds__(256) void bn_stats(
    const float* __restrict__ Ag, float* __restrict__ stats, int N) {
    constexpr int RPB = 256 / C;
    int c = threadIdx.x % C;
    int rg = threadIdx.x / C;
    float s = 0.f, s2 = 0.f;
    for (int r = blockIdx.x * RPB + rg; r < N; r += gridDim.x * RPB) {
        float x = Ag[(size_t)r * C + c];
        s += x;
        s2 += x * x;
    }
    __shared__ float ls[256], ls2[256];
    ls[threadIdx.x] = s;
    ls2[threadIdx.x] = s2;
    __syncthreads();
    if (rg == 0) {
#pragma unroll
        for (int g = 1; g < RPB; ++g) {
            s += ls[g * C + c];
            s2 += ls2[g * C + c];
        }
        atomicAdd(&stats[c], s);
        atomicAdd(&stats[C + c], s2);
    }
}

// ---------------------------------------------------------------------------
// BN normalize IN PLACE: x = (x - mean) * rsqrt(max(var,0) + eps)
// ---------------------------------------------------------------------------
template <int C>
__global__ __launch_bounds__(256) void bn_norm(
    float* __restrict__ Ag, const float* __restrict__ stats, int N) {
    constexpr int RPB = 256 / C;
    int c = threadIdx.x % C;
    int rg = threadIdx.x / C;
    float invN = 1.f / (float)N;
    float mean = stats[c] * invN;
    float var = stats[C + c] * invN - mean * mean;
    float inv = rsqrtf(fmaxf(var, 0.f) + 1e-5f);
    for (int r = blockIdx.x * RPB + rg; r < N; r += gridDim.x * RPB) {
        float x = Ag[(size_t)r * C + c];
        Ag[(size_t)r * C + c] = (x - mean) * inv;
    }
}

// ---------------------------------------------------------------------------
extern "C" void kernel_launch(void* const* d_in, const int* in_sizes, int n_in,
                              void* d_out, int out_size, void* d_ws,
                              size_t ws_size, hipStream_t stream) {
    const float* x = (const float*)d_in[0];
    const int* adj_row = (const int*)d_in[1];
    const int* adj_col = (const int*)d_in[2];
    const float* adj_vals = (const float*)d_in[3];
    const float* W1 = (const float*)d_in[4];
    const float* W2 = (const float*)d_in[5];
    const float* W3 = (const float*)d_in[6];
    const float* W4 = (const float*)d_in[7];

    int N = in_sizes[0] / 256;
    int E = in_sizes[1];

    // workspace carve: rp | stats | S(bf16)   (~26 MB total)
    char* ws = (char*)d_ws;
    int* rp = (int*)ws;
    size_t off = (((size_t)(N + 1) * 4) + 255) & ~(size_t)255;
    float* stats = (float*)(ws + off);  // 4 layers x 256 floats
    off += 4 * 256 * sizeof(float);
    unsigned short* S = (unsigned short*)(ws + off);  // support, N*128 bf16

    hipMemsetAsync(stats, 0, 4 * 256 * sizeof(float), stream);
    build_rowptr<<<(E + 255) / 256, 256, 0, stream>>>(adj_row, rp, E, N);

    float* h1 = (float*)d_out;
    float* h2 = h1 + (size_t)N * 128;
    float* h3 = h2 + (size_t)N * 128;
    float* h4 = h3 + (size_t)N * 64;

    int gblk = (N + 63) / 64;

    // layer 1: 256 -> 128
    gemm_mfma<256, 128><<<gblk, 256, 0, stream>>>(x, W1, S, N);
    spmm_act_b<128><<<(N + 7) / 8, 256, 0, stream>>>(
        (const ushortx4*)S, adj_col, adj_vals, rp, h1, N);
    bn_stats<128><<<256, 256, 0, stream>>>(h1, stats + 0, N);
    bn_norm<128><<<256, 256, 0, stream>>>(h1, stats + 0, N);

    // layer 2: 128 -> 128
    gemm_mfma<128, 128><<<gblk, 256, 0, stream>>>(h1, W2, S, N);
    spmm_act_b<128><<<(N + 7) / 8, 256, 0, stream>>>(
        (const ushortx4*)S, adj_col, adj_vals, rp, h2, N);
    bn_stats<128><<<256, 256, 0, stream>>>(h2, stats + 256, N);
    bn_norm<128><<<256, 256, 0, stream>>>(h2, stats + 256, N);

    // layer 3: 128 -> 64
    gemm_mfma<128, 64><<<gblk, 256, 0, stream>>>(h2, W3, S, N);
    spmm_act_b<64><<<(N + 15) / 16, 256, 0, stream>>>(
        (const ushortx4*)S, adj_col, adj_vals, rp, h3, N);
    bn_stats<64><<<256, 256, 0, stream>>>(h3, stats + 512, N);
    bn_norm<64><<<256, 256, 0, stream>>>(h3, stats + 512, N);

    // layer 4: 64 -> 32
    gemm_mfma<64, 32><<<gblk, 256, 0, stream>>>(h3, W4, S, N);
    spmm_act_b<32><<<(N + 31) / 32, 256, 0, stream>>>(
        (const ushortx4*)S, adj_col, adj_vals, rp, h4, N);
    bn_stats<32><<<256, 256, 0, stream>>>(h4, stats + 768, N);
    bn_norm<32><<<256, 256, 0, stream>>>(h4, stats + 768, N);
}